// Round 2
// baseline (2592.866 us; speedup 1.0000x reference)
//
#include <hip/hip_runtime.h>
#include <hip/hip_bf16.h>
#include <math.h>

// ---------------------------------------------------------------------------
// MoE trading transformer forward, MI355X/gfx950.
// B=16 S=512 F_IN=46 D=256 H=8 (dh=32) L=6 E=8 DFF=1024 OUT=3.
// Output: action(16x3) | profit(16x1) | aux_total(1)  = 65 elements.
//
// Input storage dtype (f32 vs bf16) is detected AT RUNTIME by sniff_kernel
// (low-half bf16 exponent sanity test on x), then all 41 inputs are
// canonicalized to bf16 in ws; the pipeline runs on the canonical copies
// and the output is emitted in the detected dtype.
//
// Workspace layout (~40.6 MB used):
//   [0,4M)        h           bf16 8192x256
//   [4M,12M)      moe_acc     f32  8192x256
//   [12M,+256K)   gate_w      f32  8192x8
//   [12M+256K)    aux_sums    f32 48 | flag int | out_stage f32 65
//   [13M,29M)     region X: qkv bf16 8192x768 (12M) | attn_out (4M at +12M)
//                 reused: proj_out (4M at +0), then hid bf16 8192x1024 (16M)
//   [29M,+16K)    pooled_attn bf16 16x256 ; pooled bf16 16x256
//   [30M,~40.6M)  canonical bf16 copies of all 41 inputs
// ---------------------------------------------------------------------------

typedef __bf16 bf16;
typedef __bf16 bf16x8 __attribute__((ext_vector_type(8)));
typedef float f32x4 __attribute__((ext_vector_type(4)));

#define NIN 41

struct InTab {
    const void* src[NIN];
    unsigned off[NIN];
    unsigned n[NIN];
};

__device__ __forceinline__ float gelu_exact(float x) {
    return 0.5f * x * (1.0f + erff(x * 0.70710678118654752f));
}

// ---------------------------------------------------------------------------
// Dtype sniffer: read 256 u32 words of x. Low 16 bits as bf16: if storage is
// bf16, these are genuine N(0,1) values (sane exponent ~always); if storage is
// f32, they are mantissa bits (sane exponent ~10%). flag: 1=bf16, 0=f32.
// ---------------------------------------------------------------------------
__global__ void sniff_kernel(const unsigned* __restrict__ xw, int* __restrict__ flag) {
    __shared__ int cnt;
    if (threadIdx.x == 0) cnt = 0;
    __syncthreads();
    const unsigned w = xw[threadIdx.x];
    const unsigned ex = (w >> 7) & 0xFFu;           // exponent of low-half bf16
    if (ex >= 107u && ex <= 133u) atomicAdd(&cnt, 1);
    __syncthreads();
    if (threadIdx.x == 0) *flag = (cnt >= 192) ? 1 : 0;
}

// Canonicalize input inp (grid.y) to bf16 at dst_base+off. 4 elems/thread.
__global__ __launch_bounds__(256) void convert_kernel(
    InTab tab, bf16* __restrict__ dst_base, const int* __restrict__ flag) {
    const int inp = blockIdx.y;
    const unsigned n = tab.n[inp];
    const unsigned i0 = (blockIdx.x * 256u + threadIdx.x) * 4u;
    if (i0 >= n) return;
    const int isbf = *flag;
    bf16* dst = dst_base + tab.off[inp];
    const unsigned end = (i0 + 4u > n) ? n : i0 + 4u;
    if (isbf) {
        const unsigned short* s = (const unsigned short*)tab.src[inp];
        for (unsigned i = i0; i < end; i++) ((unsigned short*)dst)[i] = s[i];
    } else {
        const float* s = (const float*)tab.src[inp];
        for (unsigned i = i0; i < end; i++) dst[i] = (bf16)s[i];
    }
}

__global__ void out_convert_kernel(const float* __restrict__ st, void* __restrict__ out,
                                   const int* __restrict__ flag) {
    const int i = threadIdx.x;
    if (i >= 65) return;
    if (*flag) ((bf16*)out)[i] = (bf16)st[i];
    else       ((float*)out)[i] = st[i];
}

// ---------------------------------------------------------------------------
// Generic MFMA GEMM:  C[M,N] = act(A[M,K] @ W[N,K]^T + bias[N])
// CMODE 0: store bf16 C.
// CMODE 1: Cf32[m,n]  = rowscale[m*8] * (acc + bias[n])   (expert 0)
// CMODE 2: Cf32[m,n] += rowscale[m*8] * (acc + bias[n])   (experts 1..7)
// ---------------------------------------------------------------------------
template <int BM, int BN, int WM, int WN, int CMODE, bool GELU>
__global__ __launch_bounds__(256) void gemm_bt(
    const bf16* __restrict__ A, const bf16* __restrict__ W,
    const bf16* __restrict__ bias, void* __restrict__ C,
    int M, int N, int K, const float* __restrict__ rowscale) {
    constexpr int BK = 64;
    __shared__ alignas(16) bf16 As[BM][BK + 8];
    __shared__ alignas(16) bf16 Ws[BN][BK + 8];
    const int bm0 = blockIdx.x * BM, bn0 = blockIdx.y * BN;
    const int tid = threadIdx.x;
    const int wave = tid >> 6, lane = tid & 63;
    constexpr int WCOLS = BN / WN;
    const int wm0 = (wave / WCOLS) * WM, wn0 = (wave % WCOLS) * WN;
    constexpr int MT = WM / 16, NT = WN / 16;
    f32x4 acc[MT][NT] = {};
    const int lrow = tid >> 3, lcol = (tid & 7) * 8;
    const int frow = lane & 15, fquad = lane >> 4;

    for (int k0 = 0; k0 < K; k0 += BK) {
#pragma unroll
        for (int p = 0; p < BM / 32; p++)
            *(bf16x8*)&As[lrow + p * 32][lcol] =
                *(const bf16x8*)&A[(size_t)(bm0 + lrow + p * 32) * K + k0 + lcol];
#pragma unroll
        for (int p = 0; p < BN / 32; p++)
            *(bf16x8*)&Ws[lrow + p * 32][lcol] =
                *(const bf16x8*)&W[(size_t)(bn0 + lrow + p * 32) * K + k0 + lcol];
        __syncthreads();
#pragma unroll
        for (int ks = 0; ks < BK / 32; ks++) {
            bf16x8 af[MT], bfr[NT];
#pragma unroll
            for (int mt = 0; mt < MT; mt++)
                af[mt] = *(const bf16x8*)&As[wm0 + mt * 16 + frow][ks * 32 + fquad * 8];
#pragma unroll
            for (int nt = 0; nt < NT; nt++)
                bfr[nt] = *(const bf16x8*)&Ws[wn0 + nt * 16 + frow][ks * 32 + fquad * 8];
#pragma unroll
            for (int mt = 0; mt < MT; mt++)
#pragma unroll
                for (int nt = 0; nt < NT; nt++)
                    acc[mt][nt] = __builtin_amdgcn_mfma_f32_16x16x32_bf16(
                        af[mt], bfr[nt], acc[mt][nt], 0, 0, 0);
        }
        __syncthreads();
    }

#pragma unroll
    for (int mt = 0; mt < MT; mt++) {
#pragma unroll
        for (int nt = 0; nt < NT; nt++) {
            const int gn = bn0 + wn0 + nt * 16 + frow;
            const float bv = (float)bias[gn];
#pragma unroll
            for (int r = 0; r < 4; r++) {
                const int gm = bm0 + wm0 + mt * 16 + fquad * 4 + r;
                float v = acc[mt][nt][r] + bv;
                if (GELU) v = gelu_exact(v);
                if (CMODE == 0) {
                    ((bf16*)C)[(size_t)gm * N + gn] = (bf16)v;
                } else {
                    float* Cf = (float*)C;
                    const float s = rowscale[(size_t)gm * 8];
                    if (CMODE == 1)
                        Cf[(size_t)gm * N + gn] = s * v;
                    else
                        Cf[(size_t)gm * N + gn] += s * v;
                }
            }
        }
    }
}

// ---------------------------------------------------------------------------
// Input projection + sinusoidal positional encoding. grid 8192, block 256.
// ---------------------------------------------------------------------------
__global__ __launch_bounds__(256) void input_proj_kernel(
    const bf16* __restrict__ x, const bf16* __restrict__ w,
    const bf16* __restrict__ b, bf16* __restrict__ h) {
    const int m = blockIdx.x, t = threadIdx.x;
    __shared__ float xs[46];
    if (t < 46) xs[t] = (float)x[m * 46 + t];
    __syncthreads();
    float acc = (float)b[t];
#pragma unroll
    for (int k = 0; k < 46; k++) acc += xs[k] * (float)w[t * 46 + k];
    const int s = m & 511;
    const int i = t >> 1;
    const float dv = expf((float)(2 * i) * (-9.210340371976184f / 256.0f));
    const float ang = (float)s * dv;
    const float pe = (t & 1) ? cosf(ang) : sinf(ang);
    h[(size_t)m * 256 + t] = (bf16)(acc + pe);
}

// ---------------------------------------------------------------------------
// LayerNorm with residual add:  h = LN(h + add) * s + b. grid 8192, block 256.
// ---------------------------------------------------------------------------
template <bool ADDF32>
__global__ __launch_bounds__(256) void ln_kernel(
    bf16* __restrict__ h, const void* __restrict__ add,
    const bf16* __restrict__ s, const bf16* __restrict__ b) {
    const int m = blockIdx.x, t = threadIdx.x;
    float x = (float)h[(size_t)m * 256 + t];
    if (ADDF32)
        x += ((const float*)add)[(size_t)m * 256 + t];
    else
        x += (float)((const bf16*)add)[(size_t)m * 256 + t];
    float s1 = x, s2 = x * x;
#pragma unroll
    for (int msk = 1; msk < 64; msk <<= 1) {
        s1 += __shfl_xor(s1, msk, 64);
        s2 += __shfl_xor(s2, msk, 64);
    }
    __shared__ float w1[4], w2[4];
    if ((t & 63) == 0) { w1[t >> 6] = s1; w2[t >> 6] = s2; }
    __syncthreads();
    s1 = w1[0] + w1[1] + w1[2] + w1[3];
    s2 = w2[0] + w2[1] + w2[2] + w2[3];
    const float mean = s1 * (1.0f / 256.0f);
    const float var = fmaxf(s2 * (1.0f / 256.0f) - mean * mean, 0.0f);
    const float inv = rsqrtf(var + 1e-5f);
    h[(size_t)m * 256 + t] = (bf16)((x - mean) * inv * (float)s[t] + (float)b[t]);
}

// ---------------------------------------------------------------------------
// Gate: logits, top-2 softmax weights (f32, zero for unrouted), aux partials.
// ---------------------------------------------------------------------------
__global__ __launch_bounds__(256) void gate_kernel(
    const bf16* __restrict__ h, const bf16* __restrict__ gw,
    const bf16* __restrict__ gb, float* __restrict__ gatew,
    float* __restrict__ aux_sums) {
    __shared__ float lg[32][8];
    __shared__ float psum[8];
    const int tid = threadIdx.x;
    const int tok = blockIdx.x * 32 + (tid >> 3), e = tid & 7;
    float acc = 0.0f;
    for (int k = 0; k < 256; k += 8) {
        bf16x8 hv = *(const bf16x8*)&h[(size_t)tok * 256 + k];
        bf16x8 wv = *(const bf16x8*)&gw[e * 256 + k];
#pragma unroll
        for (int j = 0; j < 8; j++) acc += (float)hv[j] * (float)wv[j];
    }
    lg[tid >> 3][e] = acc + (float)gb[e];
    if (tid < 8) psum[tid] = 0.0f;
    __syncthreads();
    if (tid < 32) {
        const int t2 = blockIdx.x * 32 + tid;
        float l[8];
#pragma unroll
        for (int j = 0; j < 8; j++) l[j] = lg[tid][j];
        int i0 = 0;
#pragma unroll
        for (int j = 1; j < 8; j++)
            if (l[j] > l[i0]) i0 = j;
        int i1 = -1;
#pragma unroll
        for (int j = 0; j < 8; j++)
            if (j != i0 && (i1 < 0 || l[j] > l[i1])) i1 = j;
        const float p0 = 1.0f / (1.0f + expf(l[i1] - l[i0]));
#pragma unroll
        for (int j = 0; j < 8; j++) {
            float wj = (j == i0) ? p0 : ((j == i1) ? (1.0f - p0) : 0.0f);
            gatew[(size_t)t2 * 8 + j] = wj;
        }
        const float mx = l[i0];
        float se = 0.0f, pe[8];
#pragma unroll
        for (int j = 0; j < 8; j++) { pe[j] = expf(l[j] - mx); se += pe[j]; }
        const float inv = 1.0f / se;
#pragma unroll
        for (int j = 0; j < 8; j++) atomicAdd(&psum[j], pe[j] * inv);
    }
    __syncthreads();
    if (tid < 8) atomicAdd(&aux_sums[tid], psum[tid]);
}

// ---------------------------------------------------------------------------
// Fused attention for one (b,h), 32-query tile. grid (16, 128), block 256.
// ---------------------------------------------------------------------------
__global__ __launch_bounds__(256) void attn_kernel(
    const bf16* __restrict__ qkv, bf16* __restrict__ aout) {
    __shared__ alignas(16) bf16 P[32][520];
    const int s0 = blockIdx.x * 32;
    const int b = blockIdx.y >> 3, hh = blockIdx.y & 7;
    const int tid = threadIdx.x, wave = tid >> 6, lane = tid & 63;
    const int frow = lane & 15, fquad = lane >> 4;
    const size_t base = (size_t)b * 512;
    const float scale = 0.17677669529663687f;  // 1/sqrt(32)

    bf16x8 qf[2];
#pragma unroll
    for (int mt = 0; mt < 2; mt++)
        qf[mt] = *(const bf16x8*)&qkv[(base + s0 + mt * 16 + frow) * 768 + hh * 32 + fquad * 8];
#pragma unroll
    for (int k8 = 0; k8 < 8; k8++) {
        const int key0 = (wave * 8 + k8) * 16;
        bf16x8 kf = *(const bf16x8*)&qkv[(base + key0 + frow) * 768 + 256 + hh * 32 + fquad * 8];
#pragma unroll
        for (int mt = 0; mt < 2; mt++) {
            f32x4 c = {};
            c = __builtin_amdgcn_mfma_f32_16x16x32_bf16(qf[mt], kf, c, 0, 0, 0);
#pragma unroll
            for (int r = 0; r < 4; r++)
                P[mt * 16 + fquad * 4 + r][key0 + frow] = (bf16)(c[r] * scale);
        }
    }
    __syncthreads();

    {   // softmax: 8 threads/row, 64 cols each
        const int row = tid >> 3, off = (tid & 7) * 64;
        float mx = -1e30f;
        for (int j = 0; j < 64; j++) mx = fmaxf(mx, (float)P[row][off + j]);
#pragma unroll
        for (int msk = 1; msk < 8; msk <<= 1) mx = fmaxf(mx, __shfl_xor(mx, msk, 64));
        float se = 0.0f;
        for (int j = 0; j < 64; j++) se += expf((float)P[row][off + j] - mx);
#pragma unroll
        for (int msk = 1; msk < 8; msk <<= 1) se += __shfl_xor(se, msk, 64);
        const float inv = 1.0f / se;
        for (int j = 0; j < 64; j++)
            P[row][off + j] = (bf16)(expf((float)P[row][off + j] - mx) * inv);
    }
    __syncthreads();

    {   // O = P V
        const int mt = wave >> 1, nt = wave & 1;
        f32x4 o = {};
        for (int ks = 0; ks < 16; ks++) {
            bf16x8 pf = *(const bf16x8*)&P[mt * 16 + frow][ks * 32 + fquad * 8];
            bf16x8 vf;
#pragma unroll
            for (int j = 0; j < 8; j++)
                vf[j] = qkv[(base + ks * 32 + fquad * 8 + j) * 768 + 512 + hh * 32 + nt * 16 + frow];
            o = __builtin_amdgcn_mfma_f32_16x16x32_bf16(pf, vf, o, 0, 0, 0);
        }
#pragma unroll
        for (int r = 0; r < 4; r++)
            aout[(base + s0 + mt * 16 + fquad * 4 + r) * 256 + hh * 32 + nt * 16 + frow] = (bf16)o[r];
    }
}

// ---------------------------------------------------------------------------
// Pooled attention: 1 query (last token) per (b,h); one wave per (b,h).
// ---------------------------------------------------------------------------
__global__ __launch_bounds__(256) void pooled_attn_kernel(
    const bf16* __restrict__ qkv, bf16* __restrict__ pa) {
    const int wid = blockIdx.x * 4 + (threadIdx.x >> 6);
    const int lane = threadIdx.x & 63;
    const int b = wid >> 3, hh = wid & 7;
    const size_t base = (size_t)b * 512;
    const float scale = 0.17677669529663687f;
    float q[32];
#pragma unroll
    for (int d = 0; d < 32; d++) q[d] = (float)qkv[(base + 511) * 768 + hh * 32 + d];
    float sc[8];
    float mx = -1e30f;
#pragma unroll
    for (int j = 0; j < 8; j++) {
        const int key = lane + j * 64;
        const bf16* kr = &qkv[(base + key) * 768 + 256 + hh * 32];
        float s = 0.0f;
#pragma unroll
        for (int d = 0; d < 32; d++) s += q[d] * (float)kr[d];
        s *= scale;
        sc[j] = s;
        mx = fmaxf(mx, s);
    }
#pragma unroll
    for (int m = 1; m < 64; m <<= 1) mx = fmaxf(mx, __shfl_xor(mx, m, 64));
    float se = 0.0f;
#pragma unroll
    for (int j = 0; j < 8; j++) { sc[j] = expf(sc[j] - mx); se += sc[j]; }
#pragma unroll
    for (int m = 1; m < 64; m <<= 1) se += __shfl_xor(se, m, 64);
    float o[32] = {};
#pragma unroll
    for (int j = 0; j < 8; j++) {
        const int key = lane + j * 64;
        const bf16* vr = &qkv[(base + key) * 768 + 512 + hh * 32];
#pragma unroll
        for (int d = 0; d < 32; d++) o[d] += sc[j] * (float)vr[d];
    }
#pragma unroll
    for (int d = 0; d < 32; d++) {
#pragma unroll
        for (int m = 1; m < 64; m <<= 1) o[d] += __shfl_xor(o[d], m, 64);
    }
    if (lane == 0) {
        const float inv = 1.0f / se;
        for (int d = 0; d < 32; d++) pa[b * 256 + hh * 32 + d] = (bf16)(o[d] * inv);
    }
}

__global__ __launch_bounds__(256) void pooled_proj_kernel(
    const bf16* __restrict__ pa, const bf16* __restrict__ w,
    const bf16* __restrict__ bias, bf16* __restrict__ pooled) {
    const int b = blockIdx.x, t = threadIdx.x;
    __shared__ float xs[256];
    xs[t] = (float)pa[b * 256 + t];
    __syncthreads();
    float acc = (float)bias[t];
    for (int k = 0; k < 256; k++) acc += xs[k] * (float)w[t * 256 + k];
    pooled[b * 256 + t] = (bf16)acc;
}

// ---------------------------------------------------------------------------
// Action + profit heads. grid 16 (batch), block 256. Writes f32 staging.
// ---------------------------------------------------------------------------
__global__ __launch_bounds__(256) void heads_kernel(
    const bf16* __restrict__ pooled,
    const bf16* __restrict__ aw1, const bf16* __restrict__ ab1,
    const bf16* __restrict__ aln1s, const bf16* __restrict__ aln1b,
    const bf16* __restrict__ aw2, const bf16* __restrict__ ab2,
    const bf16* __restrict__ aln2s, const bf16* __restrict__ aln2b,
    const bf16* __restrict__ aw3, const bf16* __restrict__ ab3,
    const bf16* __restrict__ pw1, const bf16* __restrict__ pb1,
    const bf16* __restrict__ pln1s, const bf16* __restrict__ pln1b,
    const bf16* __restrict__ pw2, const bf16* __restrict__ pb2,
    const bf16* __restrict__ pln2s, const bf16* __restrict__ pln2b,
    const bf16* __restrict__ pw3, const bf16* __restrict__ pb3,
    float* __restrict__ out) {
    const int b = blockIdx.x, t = threadIdx.x;
    __shared__ float pool[256], buf[256], buf2[256], r1[256], r2[256];
    pool[t] = (float)pooled[b * 256 + t];
    __syncthreads();

    auto block_ln = [&](float* v, int W, const bf16* ls, const bf16* lb) {
        const float val = (t < W) ? v[t] : 0.0f;
        r1[t] = val;
        r2[t] = val * val;
        __syncthreads();
        for (int off = 128; off > 0; off >>= 1) {
            if (t < off) { r1[t] += r1[t + off]; r2[t] += r2[t + off]; }
            __syncthreads();
        }
        const float mean = r1[0] / (float)W;
        const float var = fmaxf(r2[0] / (float)W - mean * mean, 0.0f);
        const float inv = rsqrtf(var + 1e-5f);
        __syncthreads();
        if (t < W) v[t] = (val - mean) * inv * (float)ls[t] + (float)lb[t];
        __syncthreads();
    };

    float a;
    if (t < 128) {
        a = (float)ab1[t];
        for (int k = 0; k < 256; k++) a += pool[k] * (float)aw1[t * 256 + k];
        buf[t] = gelu_exact(a);
    }
    __syncthreads();
    block_ln(buf, 128, aln1s, aln1b);
    if (t < 64) {
        a = (float)ab2[t];
        for (int k = 0; k < 128; k++) a += buf[k] * (float)aw2[t * 128 + k];
        buf2[t] = gelu_exact(a);
    }
    __syncthreads();
    block_ln(buf2, 64, aln2s, aln2b);
    if (t < 3) {
        a = (float)ab3[t];
        for (int k = 0; k < 64; k++) a += buf2[k] * (float)aw3[t * 64 + k];
        out[b * 3 + t] = a;
    }

    a = (float)pb1[t];
    for (int k = 0; k < 256; k++) a += pool[k] * (float)pw1[t * 256 + k];
    buf[t] = a;
    __syncthreads();
    block_ln(buf, 256, pln1s, pln1b);
    buf[t] = gelu_exact(buf[t]);
    __syncthreads();
    if (t < 128) {
        a = (float)pb2[t];
        for (int k = 0; k < 256; k++) a += buf[k] * (float)pw2[t * 256 + k];
        buf2[t] = a;
    }
    __syncthreads();
    block_ln(buf2, 128, pln2s, pln2b);
    if (t < 128) buf2[t] = gelu_exact(buf2[t]);
    __syncthreads();
    if (t == 0) {
        a = (float)pb3[0];
        for (int k = 0; k < 128; k++) a += buf2[k] * (float)pw3[k];
        out[48 + b] = a;
    }
}

__global__ void aux_kernel(const float* __restrict__ sums, float* __restrict__ out) {
    if (threadIdx.x == 0 && blockIdx.x == 0) {
        float tot = 0.0f;
        for (int l = 0; l < 6; l++)
            for (int e = 0; e < 8; e++) {
                const float mn = sums[l * 8 + e] * (1.0f / 8192.0f);
                tot += 8.0f * mn * mn;
            }
        out[64] = tot;
    }
}

// ---------------------------------------------------------------------------
extern "C" void kernel_launch(void* const* d_in, const int* in_sizes, int n_in,
                              void* d_out, int out_size, void* d_ws, size_t ws_size,
                              hipStream_t stream) {
    char* ws = (char*)d_ws;
    const size_t MB = 1024 * 1024;
    bf16*  h      = (bf16*)(ws);
    float* moe    = (float*)(ws + 4 * MB);
    float* gatew  = (float*)(ws + 12 * MB);
    float* auxs   = (float*)(ws + 12 * MB + 256 * 1024);
    int*   flag   = (int*)(ws + 12 * MB + 260 * 1024);
    float* ostage = (float*)(ws + 12 * MB + 264 * 1024);
    bf16*  qkv    = (bf16*)(ws + 13 * MB);
    bf16*  aout   = (bf16*)(ws + 13 * MB + 12 * MB);
    bf16*  projo  = (bf16*)(ws + 13 * MB);
    bf16*  hid    = (bf16*)(ws + 13 * MB);
    bf16*  pattn  = (bf16*)(ws + 29 * MB);
    bf16*  pooled = (bf16*)(ws + 29 * MB + 8192);
    bf16*  cvbase = (bf16*)(ws + 30 * MB);

    // build the canonicalization table (host-side arithmetic only)
    InTab tab;
    unsigned off = 0;
    bf16* cv[NIN];
    for (int i = 0; i < NIN; i++) {
        tab.src[i] = d_in[i];
        tab.off[i] = off;
        tab.n[i] = (unsigned)in_sizes[i];
        cv[i] = cvbase + off;
        off += ((unsigned)in_sizes[i] + 7u) & ~7u;
    }

    const bf16 *x = cv[0], *in_w = cv[1], *in_b = cv[2], *qkv_w = cv[3], *qkv_b = cv[4],
               *out_w = cv[5], *out_b = cv[6], *gate_w = cv[7], *gate_b = cv[8],
               *e_w1 = cv[9], *e_b1 = cv[10], *e_w2 = cv[11], *e_b2 = cv[12],
               *ln1_s = cv[13], *ln1_b = cv[14], *ln2_s = cv[15], *ln2_b = cv[16],
               *pqkv_w = cv[17], *pqkv_b = cv[18], *pout_w = cv[19], *pout_b = cv[20],
               *a_w1 = cv[21], *a_b1 = cv[22], *a_ln1s = cv[23], *a_ln1b = cv[24],
               *a_w2 = cv[25], *a_b2 = cv[26], *a_ln2s = cv[27], *a_ln2b = cv[28],
               *a_w3 = cv[29], *a_b3 = cv[30],
               *pr_w1 = cv[31], *pr_b1 = cv[32], *pr_ln1s = cv[33], *pr_ln1b = cv[34],
               *pr_w2 = cv[35], *pr_b2 = cv[36], *pr_ln2s = cv[37], *pr_ln2b = cv[38],
               *pr_w3 = cv[39], *pr_b3 = cv[40];

    sniff_kernel<<<1, 256, 0, stream>>>((const unsigned*)d_in[0], flag);
    convert_kernel<<<dim3(2048, NIN), 256, 0, stream>>>(tab, cvbase, flag);

    hipMemsetAsync(auxs, 0, 64 * sizeof(float), stream);
    input_proj_kernel<<<8192, 256, 0, stream>>>(x, in_w, in_b, h);

    for (int l = 0; l < 6; l++) {
        gemm_bt<128, 128, 64, 64, 0, false><<<dim3(64, 6), 256, 0, stream>>>(
            h, qkv_w, qkv_b, qkv, 8192, 768, 256, nullptr);
        attn_kernel<<<dim3(16, 128), 256, 0, stream>>>(qkv, aout);
        gemm_bt<128, 64, 32, 64, 0, false><<<dim3(64, 4), 256, 0, stream>>>(
            aout, out_w, out_b, projo, 8192, 256, 256, nullptr);
        ln_kernel<false><<<8192, 256, 0, stream>>>(h, projo, ln1_s, ln1_b);
        gate_kernel<<<256, 256, 0, stream>>>(h, gate_w, gate_b, gatew, auxs + l * 8);
        for (int e = 0; e < 8; e++) {
            gemm_bt<128, 128, 64, 64, 0, true><<<dim3(64, 8), 256, 0, stream>>>(
                h, e_w1 + (size_t)e * 1024 * 256, e_b1 + e * 1024, hid,
                8192, 1024, 256, nullptr);
            if (e == 0)
                gemm_bt<128, 64, 32, 64, 1, false><<<dim3(64, 4), 256, 0, stream>>>(
                    hid, e_w2 + (size_t)e * 256 * 1024, e_b2 + e * 256, moe,
                    8192, 256, 1024, gatew + e);
            else
                gemm_bt<128, 64, 32, 64, 2, false><<<dim3(64, 4), 256, 0, stream>>>(
                    hid, e_w2 + (size_t)e * 256 * 1024, e_b2 + e * 256, moe,
                    8192, 256, 1024, gatew + e);
        }
        ln_kernel<true><<<8192, 256, 0, stream>>>(h, moe, ln2_s, ln2_b);
    }

    gemm_bt<128, 128, 64, 64, 0, false><<<dim3(64, 6), 256, 0, stream>>>(
        h, pqkv_w, pqkv_b, qkv, 8192, 768, 256, nullptr);
    pooled_attn_kernel<<<32, 256, 0, stream>>>(qkv, pattn);
    pooled_proj_kernel<<<16, 256, 0, stream>>>(pattn, pout_w, pout_b, pooled);

    heads_kernel<<<16, 256, 0, stream>>>(
        pooled,
        a_w1, a_b1, a_ln1s, a_ln1b, a_w2, a_b2, a_ln2s, a_ln2b, a_w3, a_b3,
        pr_w1, pr_b1, pr_ln1s, pr_ln1b, pr_w2, pr_b2, pr_ln2s, pr_ln2b, pr_w3, pr_b3,
        ostage);
    aux_kernel<<<1, 64, 0, stream>>>(auxs, ostage);
    out_convert_kernel<<<1, 128, 0, stream>>>(ostage, d_out, flag);
}